// Round 7
// baseline (94.741 us; speedup 1.0000x reference)
//
#include <hip/hip_runtime.h>

typedef __bf16 bf16x8 __attribute__((ext_vector_type(8)));
typedef float f32x4 __attribute__((ext_vector_type(4)));
typedef unsigned int u32;

constexpr int Bc = 2, Sc = 2048, Hc = 16, Dc = 64;
constexpr int QBLK = 64, KVBLK = 64;
constexpr int NT = Sc / QBLK;          // 32 q-tiles
constexpr int ROWSTR = 3 * Hc * Dc;    // 3072 floats between consecutive s
constexpr float QSCALE = 0.125f * 1.4426950408889634f;  // 1/sqrt(D) * log2e

// MFMA f32_16x16x32_bf16 layouts (learn_hip m89/m97):
//   A[m][k]: lane l, elem j -> m = l&15,        k = 8*(l>>4) + j
//   B[k][n]: lane l, elem j -> k = 8*(l>>4)+j,  n = l&15
//   C/D[m][n]: lane l, reg r -> m = (l>>4)*4+r, n = l&15

// DPP cross-lane on the VALU pipe (no DS ops).
template <int CTRL>
static __device__ __forceinline__ float dppf(float x) {
  int xi = __builtin_bit_cast(int, x);
  return __builtin_bit_cast(float,
      __builtin_amdgcn_update_dpp(xi, xi, CTRL, 0xF, 0xF, false));
}
static __device__ __forceinline__ float redmax16(float x) {
  x = fmaxf(x, dppf<0x121>(x));
  x = fmaxf(x, dppf<0x122>(x));
  x = fmaxf(x, dppf<0x124>(x));
  x = fmaxf(x, dppf<0x128>(x));
  return x;
}
static __device__ __forceinline__ float redsum16(float x) {
  x += dppf<0x121>(x);
  x += dppf<0x122>(x);
  x += dppf<0x124>(x);
  x += dppf<0x128>(x);
  return x;
}

static __device__ __forceinline__ u32 pack2(float a, float b) {
  unsigned short x = __builtin_bit_cast(unsigned short, (__bf16)a);
  unsigned short y = __builtin_bit_cast(unsigned short, (__bf16)b);
  return (u32)x | ((u32)y << 16);
}

__global__ __launch_bounds__(512, 4)
void fattn_kernel(const float* __restrict__ qkv, float* __restrict__ out) {
  // XCD-aware bijective swizzle (512 blocks, 512 % 8 == 0)
  const int id = blockIdx.x + blockIdx.y * gridDim.x;   // 0..511
  const int swz = (id & 7) * 64 + (id >> 3);
  const int xlow = swz & 15;            // 0..15
  const int xhigh = NT - 1 - xlow;      // 31..16 (constant 33 tile-steps/block)
  const int bh = swz >> 4;
  const int b = bh >> 4, h = bh & 15;

  const int tid = threadIdx.x;
  const int wave = tid >> 6;            // 0..7
  const int lane = tid & 63;
  const int lg = lane >> 4;             // 0..3
  const int li = lane & 15;             // 0..15
  const bool is_h = wave < 4;           // waves 0-3: H tile, 4-7: L tile
  const int sub = wave & 3;
  const int myx = is_h ? xhigh : xlow;
  const int qw = myx * QBLK + sub * 16; // this wave's 16 q-rows

  const float* qp = qkv + (size_t)b * Sc * ROWSTR + h * Dc;
  const float* kp = qp + Hc * Dc;
  const float* vp = qp + 2 * Hc * Dc;

  __shared__ __align__(16) char k_s[KVBLK * Dc * 2];   // [kv][d] bf16, XOR-swz
  __shared__ __align__(16) char v_s[Dc * KVBLK * 2];   // V^T [d][kv] bf16, XOR-swz
  __shared__ __align__(16) char p_s[8][16 * KVBLK * 2];
  char* pw = p_s[wave];

  // ---- Q fragment (one tile per wave), pre-scaled (1/sqrt(D) * log2e) ----
  bf16x8 qf[2];
  {
    const float* qr = qp + (size_t)(qw + li) * ROWSTR + 8 * lg;
#pragma unroll
    for (int fi = 0; fi < 2; ++fi) {
      f32x4 a0 = *(const f32x4*)(qr + 32 * fi);
      f32x4 a1 = *(const f32x4*)(qr + 32 * fi + 4);
      bf16x8 qa;
#pragma unroll
      for (int j = 0; j < 4; ++j) {
        qa[j] = (__bf16)(a0[j] * QSCALE); qa[j + 4] = (__bf16)(a1[j] * QSCALE);
      }
      qf[fi] = qa;
    }
  }

  f32x4 oacc[4];
  float mrow[4], lrow[4];
#pragma unroll
  for (int n = 0; n < 4; ++n) oacc[n] = f32x4{0, 0, 0, 0};
#pragma unroll
  for (int r = 0; r < 4; ++r) { mrow[r] = -1e30f; lrow[r] = 0.f; }

  for (int t = 0; t <= xhigh; ++t) {
    const int kv0 = t * KVBLK;

    // ---- staging: 512 threads cover the whole K+V tile in one pass ----
    {
      const int r = tid >> 3, g = tid & 7;
      const float* ks = kp + (size_t)(kv0 + r) * ROWSTR + g * 8;
      const float* vs = vp + (size_t)(kv0 + r) * ROWSTR + g * 8;
      f32x4 k0 = *(const f32x4*)ks;
      f32x4 k1 = *(const f32x4*)(ks + 4);
      f32x4 v0 = *(const f32x4*)vs;
      f32x4 v1 = *(const f32x4*)(vs + 4);
      bf16x8 kb;
#pragma unroll
      for (int j = 0; j < 4; ++j) { kb[j] = (__bf16)k0[j]; kb[j + 4] = (__bf16)k1[j]; }
      *(bf16x8*)(k_s + ((r * 128 + g * 16) ^ ((r & 7) << 4))) = kb;

      // V^T: pair kv rows (r, r^1) via DPP row_ror:8 (lane^8 within 16-row);
      // even r keeps d 0..3 of its octet, odd r keeps d 4..7; rotate store
      // order by g so simultaneous stores spread d&7 across banks.
      const int odd = r & 1;
      f32x4 tmp = odd ? v0 : v1;
      f32x4 rcv;
#pragma unroll
      for (int j = 0; j < 4; ++j) rcv[j] = dppf<0x128>(tmp[j]);
      const int kvb2 = (r & ~1) * 2;
#pragma unroll
      for (int s = 0; s < 4; ++s) {
        const int dj = (s + g) & 3;
        const float lo = odd ? rcv[dj] : v0[dj];
        const float hi = odd ? v1[dj] : rcv[dj];
        const int d = 8 * g + 4 * odd + dj;
        *(u32*)(v_s + ((d * 128 + kvb2) ^ ((d & 7) << 4))) = pack2(lo, hi);
      }
    }
    __syncthreads();

    if (t <= myx) {
      // ---- K fragments, QK^T ----
      f32x4 sacc[4];
#pragma unroll
      for (int n = 0; n < 4; ++n) sacc[n] = f32x4{0, 0, 0, 0};
      __builtin_amdgcn_s_setprio(1);
#pragma unroll
      for (int n = 0; n < 4; ++n) {
        const int krow = 16 * n + li;
        const int sw = (krow & 7) << 4;
#pragma unroll
        for (int fi = 0; fi < 2; ++fi) {
          bf16x8 kb = *(const bf16x8*)(k_s + ((krow * 128 + fi * 64 + lg * 16) ^ sw));
          sacc[n] = __builtin_amdgcn_mfma_f32_16x16x32_bf16(qf[fi], kb, sacc[n], 0, 0, 0);
        }
      }
      __builtin_amdgcn_s_setprio(0);

      if (t == myx) {   // diagonal tile: causal mask
        const int qrow = qw + 4 * lg;
#pragma unroll
        for (int n = 0; n < 4; ++n)
#pragma unroll
          for (int r = 0; r < 4; ++r)
            if (kv0 + 16 * n + li > qrow + r) sacc[n][r] = -1e30f;
      }

      // ---- online softmax (DPP reductions, log2 domain) ----
      float pm[4];
#pragma unroll
      for (int r = 0; r < 4; ++r) {
        pm[r] = fmaxf(fmaxf(sacc[0][r], sacc[1][r]), fmaxf(sacc[2][r], sacc[3][r]));
        pm[r] = redmax16(pm[r]);
      }

      bool need = false;
#pragma unroll
      for (int r = 0; r < 4; ++r) need = need || (pm[r] > mrow[r] + 8.0f);
      if (__any(need)) {
#pragma unroll
        for (int r = 0; r < 4; ++r) {
          float mnew = fmaxf(mrow[r], pm[r]);
          float scl = __builtin_exp2f(mrow[r] - mnew);
          mrow[r] = mnew;
          lrow[r] *= scl;
#pragma unroll
          for (int n = 0; n < 4; ++n) oacc[n][r] *= scl;
        }
      }

#pragma unroll
      for (int r = 0; r < 4; ++r) {
        float s = 0.f;
#pragma unroll
        for (int n = 0; n < 4; ++n) {
          float p = __builtin_exp2f(sacc[n][r] - mrow[r]);
          sacc[n][r] = p;
          s += p;
        }
        lrow[r] += redsum16(s);
      }

      // ---- P store [q][kv] bf16 swizzled (DPP quad_perm lane^1 pairing) ----
      {
        const int oddli = li & 1;
        const int kvoff = (li & ~1) * 2;
        const int q0 = 4 * lg + 2 * oddli;
        const int sw0 = (q0 & 7) << 4;
        const int sw1 = ((q0 + 1) & 7) << 4;
#pragma unroll
        for (int n = 0; n < 4; ++n) {
          float t0 = oddli ? sacc[n][0] : sacc[n][2];
          float t1 = oddli ? sacc[n][1] : sacc[n][3];
          float r0 = dppf<0xB1>(t0);
          float r1 = dppf<0xB1>(t1);
          float lo0 = oddli ? r0 : sacc[n][0];
          float hi0 = oddli ? sacc[n][2] : r0;
          float lo1 = oddli ? r1 : sacc[n][1];
          float hi1 = oddli ? sacc[n][3] : r1;
          const int base = n * 32 + kvoff;
          *(u32*)(pw + ((q0 * 128 + base) ^ sw0)) = pack2(lo0, hi0);
          *(u32*)(pw + (((q0 + 1) * 128 + base) ^ sw1)) = pack2(lo1, hi1);
        }
      }

      // ---- PV: P + V frags from LDS (V loaded late to cut VGPR peak) ----
#pragma unroll
      for (int ks = 0; ks < 2; ++ks) {
        const int pbyte = (li * 128 + (32 * ks + 8 * lg) * 2) ^ ((li & 7) << 4);
        bf16x8 pa = *(const bf16x8*)(pw + pbyte);
        __builtin_amdgcn_s_setprio(1);
#pragma unroll
        for (int n = 0; n < 4; ++n) {
          const int row = 16 * n + li;
          const int vbyte = (row * 128 + (32 * ks + 8 * lg) * 2) ^ ((row & 7) << 4);
          bf16x8 vb = *(const bf16x8*)(v_s + vbyte);
          oacc[n] = __builtin_amdgcn_mfma_f32_16x16x32_bf16(pa, vb, oacc[n], 0, 0, 0);
        }
        __builtin_amdgcn_s_setprio(0);
      }
    }
    __syncthreads();
  }

  // ---- epilogue: normalize and store this wave's 16 q-rows ----
#pragma unroll
  for (int r = 0; r < 4; ++r) {
    const float inv = 1.0f / lrow[r];
    float* op = out + ((size_t)(b * Sc + qw + 4 * lg + r) * Hc + h) * Dc;
#pragma unroll
    for (int n = 0; n < 4; ++n)
      op[16 * n + li] = oacc[n][r] * inv;
  }
}

extern "C" void kernel_launch(void* const* d_in, const int* in_sizes, int n_in,
                              void* d_out, int out_size, void* d_ws, size_t ws_size,
                              hipStream_t stream) {
  const float* qkv = (const float*)d_in[0];
  float* out = (float*)d_out;
  dim3 grid(NT / 2, Bc * Hc);   // (16, 32)
  fattn_kernel<<<grid, 512, 0, stream>>>(qkv, out);
}